// Round 1
// baseline (131.880 us; speedup 1.0000x reference)
//
#include <hip/hip_runtime.h>

// LIF forward scan: u = 0.5*u + x[t] - 0.5*o ; o = (u - 0.5 > 0) ? 1 : 0
// x: [32, 8192, 200] f32, time contiguous. 262144 independent rows.
// Strategy: 256 rows/block, stage 32-step time chunks through LDS so all
// global traffic is coalesced/fully-used lines; each thread runs the
// sequential recurrence for its own row out of LDS (conflict-free via +1 pad).
// Arithmetic uses __f*_rn intrinsics to forbid FMA contraction -> bit-exact
// vs numpy f32 evaluation order (spike flips near threshold are fatal).

#define STEPS 200
#define RPB 256          // rows per block == threads per block
#define LDS_STRIDE 33    // 32 + 1 pad: compute-phase bank = (tid + t) % 32

template <int CS>
__device__ __forceinline__ void process_chunk(
    const float* __restrict__ xbase,   // first row of this block
    float* __restrict__ obase,
    float* __restrict__ tile,
    int tid, int t0, float& u, float& o)
{
    constexpr int NF4 = CS / 4;        // float4s per row-chunk == float4s per thread
    float4 v[NF4];
    // ---- load phase: coalesced, all lines fully used ----
#pragma unroll
    for (int k = 0; k < NF4; ++k) {
        int f = k * RPB + tid;         // flat float4 index in the tile
        int r = f / NF4;               // tile row (power-of-2 divide -> shift)
        int c = f % NF4;
        v[k] = *reinterpret_cast<const float4*>(xbase + r * STEPS + t0 + c * 4);
    }
#pragma unroll
    for (int k = 0; k < NF4; ++k) {
        int f = k * RPB + tid;
        int r = f / NF4;
        int c = f % NF4;
        int b = r * LDS_STRIDE + c * 4;
        // bank = (r + 4c + j) % 32: 32 consecutive lanes cover all 32 banks
        tile[b + 0] = v[k].x;
        tile[b + 1] = v[k].y;
        tile[b + 2] = v[k].z;
        tile[b + 3] = v[k].w;
    }
    __syncthreads();
    // ---- compute phase: thread tid owns tile row tid ----
    {
        int rb = tid * LDS_STRIDE;
#pragma unroll
        for (int t = 0; t < CS; ++t) {
            float xi = tile[rb + t];
            // exact numpy order: ((0.5*u) + x) - (0.5*o), no FMA contraction
            float a = __fmul_rn(0.5f, u);
            float s = __fadd_rn(a, xi);
            float d = __fmul_rn(0.5f, o);
            u = __fsub_rn(s, d);
            o = (u > 0.5f) ? 1.0f : 0.0f;
            tile[rb + t] = o;          // spike back into same slot
        }
    }
    __syncthreads();
    // ---- store phase: mirror of load ----
#pragma unroll
    for (int k = 0; k < NF4; ++k) {
        int f = k * RPB + tid;
        int r = f / NF4;
        int c = f % NF4;
        int b = r * LDS_STRIDE + c * 4;
        float4 w = make_float4(tile[b + 0], tile[b + 1], tile[b + 2], tile[b + 3]);
        *reinterpret_cast<float4*>(obase + r * STEPS + t0 + c * 4) = w;
    }
    __syncthreads();                   // tile reused by next chunk's load
}

__global__ __launch_bounds__(RPB, 4) void lif_kernel(
    const float* __restrict__ x, float* __restrict__ out)
{
    __shared__ float tile[RPB * LDS_STRIDE];   // 33.8 KB -> 4 blocks/CU
    int tid = threadIdx.x;
    long long row0 = (long long)blockIdx.x * RPB;
    const float* xb = x + row0 * STEPS;
    float* ob = out + row0 * STEPS;
    float u = 0.0f, o = 0.0f;
    // 200 = 6*32 + 8
#pragma unroll
    for (int ch = 0; ch < 6; ++ch)
        process_chunk<32>(xb, ob, tile, tid, ch * 32, u, o);
    process_chunk<8>(xb, ob, tile, tid, 192, u, o);
}

extern "C" void kernel_launch(void* const* d_in, const int* in_sizes, int n_in,
                              void* d_out, int out_size, void* d_ws, size_t ws_size,
                              hipStream_t stream)
{
    const float* x = (const float*)d_in[0];
    float* out = (float*)d_out;
    int nrows = in_sizes[0] / STEPS;   // 262144
    int grid = nrows / RPB;            // 1024 blocks = 4 per CU, exact
    lif_kernel<<<grid, RPB, 0, stream>>>(x, out);
}